// Round 1
// baseline (214.191 us; speedup 1.0000x reference)
//
#include <hip/hip_runtime.h>

// Problem constants (match reference)
#define HWPX (512*512)      // pixels per batch
#define NB 2                // batches
#define NL 512              // EH*EW light directions
constexpr float PI_F = 3.14159265358979323846f;

// ws layout (bytes):
//   [0]      unsigned max-bits slot (f32 >= 0, bit-monotone)
//   [256]    float4 hmat[512]  : unit half vector (x,y,z) + sin(phi) in .w
//   [16384]  float pack[2][512][8] : {hx/max, hy/max, hz/max, 0, e0*sp/60, e1*sp/60, e2*sp/60, 0}

__global__ void k_setup1(float* __restrict__ hmat, unsigned* __restrict__ maxslot) {
    int m = threadIdx.x;            // 512 threads, one per light dir
    if (m == 0) *maxslot = 0u;
    int p = m >> 5;                 // phi index (EH=16)
    int t = m & 31;                 // theta index (EW=32)
    float phi = ((float)p * (1.0f / 16.0f)) * PI_F;
    float th  = ((float)t * (1.0f / 32.0f)) * (2.0f * PI_F);
    float sp = sinf(phi), cp = cosf(phi);
    float st = sinf(th),  ct = cosf(th);
    // l = (st*sp, cp, -ct*sp); h = l + (0,0,1), normalized
    float hx = st * sp;
    float hy = cp;
    float hz = 1.0f - ct * sp;
    float inv = rsqrtf(hx * hx + hy * hy + hz * hz);
    float4 v;
    v.x = hx * inv; v.y = hy * inv; v.z = hz * inv; v.w = sp;
    reinterpret_cast<float4*>(hmat)[m] = v;
}

__global__ __launch_bounds__(256) void k_max(const float* __restrict__ normal,
                                             const float* __restrict__ hmat,
                                             unsigned* __restrict__ maxslot) {
    int pix = blockIdx.x * 256 + threadIdx.x;      // 0 .. 2*HWPX-1
    const float* np3 = normal + (size_t)pix * 3;
    float c0 = np3[0], c1 = np3[1], c2 = np3[2];
    // channel-reversed, [0,1] -> [-1,1], L2 normalize
    float nx = (c2 - 0.5f) * 2.0f;
    float ny = (c1 - 0.5f) * 2.0f;
    float nz = (c0 - 0.5f) * 2.0f;
    float d2 = nx * nx + ny * ny + nz * nz;
    float inv = d2 > 0.0f ? rsqrtf(d2) : 0.0f;
    nx *= inv; ny *= inv; nz *= inv;

    float mx = 0.0f;
    const float4* hm = reinterpret_cast<const float4*>(hmat);
    #pragma unroll 8
    for (int m = 0; m < NL; ++m) {
        float4 h = hm[m];                          // uniform address -> scalar load
        float s = fmaf(nx, h.x, fmaf(ny, h.y, nz * h.z));
        mx = fmaxf(mx, s);
    }
    // wave-64 max reduce
    #pragma unroll
    for (int off = 32; off > 0; off >>= 1)
        mx = fmaxf(mx, __shfl_xor(mx, off));
    if ((threadIdx.x & 63) == 0)
        atomicMax(maxslot, __float_as_uint(mx));   // all candidates >= 0
}

__global__ void k_setup2(const float* __restrict__ env,
                         const float* __restrict__ hmat,
                         const unsigned* __restrict__ maxslot,
                         float* __restrict__ pack) {
    int m = threadIdx.x;            // 512 threads
    float invmax = 1.0f / __uint_as_float(*maxslot);
    float4 h = reinterpret_cast<const float4*>(hmat)[m];
    float sp = h.w;
    #pragma unroll
    for (int b = 0; b < NB; ++b) {
        float* dst = pack + ((size_t)(b * NL + m)) * 8;
        const float* e = env + ((size_t)(b * NL + m)) * 3;
        dst[0] = h.x * invmax;
        dst[1] = h.y * invmax;
        dst[2] = h.z * invmax;
        dst[3] = 0.0f;
        float c = sp * (1.0f / 60.0f);
        dst[4] = e[0] * c;
        dst[5] = e[1] * c;
        dst[6] = e[2] * c;
        dst[7] = 0.0f;
    }
}

__global__ __launch_bounds__(256) void k_shade(const float* __restrict__ normal,
                                               const float* __restrict__ pack,
                                               float* __restrict__ out) {
    int bid = blockIdx.x;
    int b = bid >> 10;                              // 1024 blocks per batch
    int pix_in_b = (bid & 1023) * 256 + (int)threadIdx.x;
    size_t pix = (size_t)b * HWPX + pix_in_b;

    const float* np3 = normal + pix * 3;
    float c0 = np3[0], c1 = np3[1], c2 = np3[2];
    float nx = (c2 - 0.5f) * 2.0f;
    float ny = (c1 - 0.5f) * 2.0f;
    float nz = (c0 - 0.5f) * 2.0f;
    float d2 = nx * nx + ny * ny + nz * nz;
    float inv = d2 > 0.0f ? rsqrtf(d2) : 0.0f;
    nx *= inv; ny *= inv; nz *= inv;

    const float* P = pack + (size_t)b * NL * 8;     // uniform per block
    float a0 = 0.0f, a1 = 0.0f, a2 = 0.0f;
    #pragma unroll 8
    for (int m = 0; m < NL; ++m) {
        float4 h = *reinterpret_cast<const float4*>(P + (size_t)m * 8);
        float4 e = *reinterpret_cast<const float4*>(P + (size_t)m * 8 + 4);
        float s = fmaf(nx, h.x, fmaf(ny, h.y, nz * h.z));
        s = fmaxf(s, 0.0f);                         // relu, already scaled by 1/max
        float s2  = s * s;
        float s4  = s2 * s2;
        float s8  = s4 * s4;
        float s16 = s8 * s8;
        float s32 = s16 * s16;
        float s64 = s32 * s32;
        a0 = fmaf(s64, e.x, a0);
        a1 = fmaf(s64, e.y, a1);
        a2 = fmaf(s64, e.z, a2);
    }
    // out[b][c][h][w]
    float* ob = out + (size_t)b * 3 * HWPX;
    ob[0 * HWPX + pix_in_b] = a0;
    ob[1 * HWPX + pix_in_b] = a1;
    ob[2 * HWPX + pix_in_b] = a2;
}

extern "C" void kernel_launch(void* const* d_in, const int* in_sizes, int n_in,
                              void* d_out, int out_size, void* d_ws, size_t ws_size,
                              hipStream_t stream) {
    const float* env    = (const float*)d_in[0];   // (B,16,32,3) f32
    const float* normal = (const float*)d_in[1];   // (B,512,512,3) f32
    float* out = (float*)d_out;                    // (B,3,512,512) f32

    char* ws = (char*)d_ws;
    unsigned* maxslot = (unsigned*)ws;
    float* hmat = (float*)(ws + 256);
    float* pack = (float*)(ws + 16384);

    int nblocks = (NB * HWPX) / 256;               // 2048

    hipLaunchKernelGGL(k_setup1, dim3(1), dim3(NL), 0, stream, hmat, maxslot);
    hipLaunchKernelGGL(k_max, dim3(nblocks), dim3(256), 0, stream, normal, hmat, maxslot);
    hipLaunchKernelGGL(k_setup2, dim3(1), dim3(NL), 0, stream, env, hmat, maxslot, pack);
    hipLaunchKernelGGL(k_shade, dim3(nblocks), dim3(256), 0, stream, normal, pack, out);
}

// Round 2
// 140.729 us; speedup vs baseline: 1.5220x; 1.5220x over previous
//
#include <hip/hip_runtime.h>

// Problem constants (match reference)
#define HWPX (512*512)      // pixels per batch
#define NB 2                // batches
#define NL 512              // EH*EW light directions
#define PXPT 4              // pixels per thread
constexpr float PI_F = 3.14159265358979323846f;

// ws layout (bytes):
//   [0]      unsigned max-bits slot (f32 >= 0, bit-monotone)
//   [256]    float4 hmat[512]  : unit half vector (x,y,z) + sin(phi) in .w
//   [16384]  float pack[2][512][8] : {hx/max, hy/max, hz/max, 0, e0*sp/60, e1*sp/60, e2*sp/60, 0}

__global__ void k_setup1(float* __restrict__ hmat, unsigned* __restrict__ maxslot) {
    int m = threadIdx.x;            // 512 threads, one per light dir
    if (m == 0) *maxslot = 0u;
    int p = m >> 5;                 // phi index (EH=16)
    int t = m & 31;                 // theta index (EW=32)
    float phi = ((float)p * (1.0f / 16.0f)) * PI_F;
    float th  = ((float)t * (1.0f / 32.0f)) * (2.0f * PI_F);
    float sp = sinf(phi), cp = cosf(phi);
    float st = sinf(th),  ct = cosf(th);
    // l = (st*sp, cp, -ct*sp); h = l + (0,0,1), normalized
    float hx = st * sp;
    float hy = cp;
    float hz = 1.0f - ct * sp;
    float inv = rsqrtf(hx * hx + hy * hy + hz * hz);
    float4 v;
    v.x = hx * inv; v.y = hy * inv; v.z = hz * inv; v.w = sp;
    reinterpret_cast<float4*>(hmat)[m] = v;
}

__device__ __forceinline__ void load_normal(const float* __restrict__ normal, size_t pix,
                                            float& nx, float& ny, float& nz) {
    const float* p = normal + pix * 3;
    float c0 = p[0], c1 = p[1], c2 = p[2];
    // channel-reversed, [0,1] -> [-1,1], L2 normalize
    float x = (c2 - 0.5f) * 2.0f;
    float y = (c1 - 0.5f) * 2.0f;
    float z = (c0 - 0.5f) * 2.0f;
    float d2 = x * x + y * y + z * z;
    float inv = d2 > 0.0f ? rsqrtf(d2) : 0.0f;
    nx = x * inv; ny = y * inv; nz = z * inv;
}

__global__ __launch_bounds__(256) void k_max(const float* __restrict__ normal,
                                             const float* __restrict__ hmat,
                                             unsigned* __restrict__ maxslot) {
    int base = blockIdx.x * (256 * PXPT) + (int)threadIdx.x;   // 4 strided pixels per thread
    float nx[PXPT], ny[PXPT], nz[PXPT];
    #pragma unroll
    for (int k = 0; k < PXPT; ++k)
        load_normal(normal, (size_t)(base + k * 256), nx[k], ny[k], nz[k]);

    float mx = 0.0f;
    const float4* hm = reinterpret_cast<const float4*>(hmat);
    #pragma unroll 8
    for (int m = 0; m < NL; ++m) {
        float4 h = hm[m];                          // uniform address
        #pragma unroll
        for (int k = 0; k < PXPT; ++k) {
            float s = fmaf(nx[k], h.x, fmaf(ny[k], h.y, nz[k] * h.z));
            mx = fmaxf(mx, s);
        }
    }
    // wave-64 max reduce
    #pragma unroll
    for (int off = 32; off > 0; off >>= 1)
        mx = fmaxf(mx, __shfl_xor(mx, off));
    if ((threadIdx.x & 63) == 0)
        atomicMax(maxslot, __float_as_uint(mx));   // all candidates >= 0
}

__global__ void k_setup2(const float* __restrict__ env,
                         const float* __restrict__ hmat,
                         const unsigned* __restrict__ maxslot,
                         float* __restrict__ pack) {
    int m = threadIdx.x;            // 512 threads
    float invmax = 1.0f / __uint_as_float(*maxslot);
    float4 h = reinterpret_cast<const float4*>(hmat)[m];
    float sp = h.w;
    #pragma unroll
    for (int b = 0; b < NB; ++b) {
        float* dst = pack + ((size_t)(b * NL + m)) * 8;
        const float* e = env + ((size_t)(b * NL + m)) * 3;
        dst[0] = h.x * invmax;
        dst[1] = h.y * invmax;
        dst[2] = h.z * invmax;
        dst[3] = 0.0f;
        float c = sp * (1.0f / 60.0f);
        dst[4] = e[0] * c;
        dst[5] = e[1] * c;
        dst[6] = e[2] * c;
        dst[7] = 0.0f;
    }
}

__global__ __launch_bounds__(256) void k_shade(const float* __restrict__ normal,
                                               const float* __restrict__ pack,
                                               float* __restrict__ out) {
    int bid = blockIdx.x;
    int blocks_per_batch = HWPX / (256 * PXPT);     // 256
    int b = bid / blocks_per_batch;
    int base_in_b = (bid % blocks_per_batch) * (256 * PXPT) + (int)threadIdx.x;

    float nx[PXPT], ny[PXPT], nz[PXPT];
    #pragma unroll
    for (int k = 0; k < PXPT; ++k)
        load_normal(normal, (size_t)b * HWPX + base_in_b + k * 256, nx[k], ny[k], nz[k]);

    const float* P = pack + (size_t)b * NL * 8;     // uniform per block
    float a0[PXPT], a1[PXPT], a2[PXPT];
    #pragma unroll
    for (int k = 0; k < PXPT; ++k) { a0[k] = 0.0f; a1[k] = 0.0f; a2[k] = 0.0f; }

    #pragma unroll 4
    for (int m = 0; m < NL; ++m) {
        float4 h = *reinterpret_cast<const float4*>(P + (size_t)m * 8);
        float4 e = *reinterpret_cast<const float4*>(P + (size_t)m * 8 + 4);
        #pragma unroll
        for (int k = 0; k < PXPT; ++k) {
            float s = fmaf(nx[k], h.x, fmaf(ny[k], h.y, nz[k] * h.z));
            s = fmaxf(s, 0.0f);                     // relu, already scaled by 1/max
            float s2  = s * s;
            float s4  = s2 * s2;
            float s8  = s4 * s4;
            float s16 = s8 * s8;
            float s32 = s16 * s16;
            float s64 = s32 * s32;
            a0[k] = fmaf(s64, e.x, a0[k]);
            a1[k] = fmaf(s64, e.y, a1[k]);
            a2[k] = fmaf(s64, e.z, a2[k]);
        }
    }
    // out[b][c][h][w]
    float* ob = out + (size_t)b * 3 * HWPX;
    #pragma unroll
    for (int k = 0; k < PXPT; ++k) {
        int p = base_in_b + k * 256;
        ob[0 * HWPX + p] = a0[k];
        ob[1 * HWPX + p] = a1[k];
        ob[2 * HWPX + p] = a2[k];
    }
}

extern "C" void kernel_launch(void* const* d_in, const int* in_sizes, int n_in,
                              void* d_out, int out_size, void* d_ws, size_t ws_size,
                              hipStream_t stream) {
    const float* env    = (const float*)d_in[0];   // (B,16,32,3) f32
    const float* normal = (const float*)d_in[1];   // (B,512,512,3) f32
    float* out = (float*)d_out;                    // (B,3,512,512) f32

    char* ws = (char*)d_ws;
    unsigned* maxslot = (unsigned*)ws;
    float* hmat = (float*)(ws + 256);
    float* pack = (float*)(ws + 16384);

    int nblocks = (NB * HWPX) / (256 * PXPT);      // 512

    hipLaunchKernelGGL(k_setup1, dim3(1), dim3(NL), 0, stream, hmat, maxslot);
    hipLaunchKernelGGL(k_max, dim3(nblocks), dim3(256), 0, stream, normal, hmat, maxslot);
    hipLaunchKernelGGL(k_setup2, dim3(1), dim3(NL), 0, stream, env, hmat, maxslot, pack);
    hipLaunchKernelGGL(k_shade, dim3(nblocks), dim3(256), 0, stream, normal, pack, out);
}

// Round 3
// 138.809 us; speedup vs baseline: 1.5431x; 1.0138x over previous
//
#include <hip/hip_runtime.h>

// Problem constants (match reference)
#define HWPX (512*512)      // pixels per batch
#define NB 2                // batches
#define NL 512              // EH*EW light directions
#define PXPT 2              // pixels per thread (2 -> 1024 blocks -> 4 waves/SIMD)
constexpr float PI_F = 3.14159265358979323846f;

// ws layout (bytes):
//   [0]      unsigned max-bits slot (f32 >= 0, bit-monotone)
//   [256]    float4 hmat[512]  : unit half vector (x,y,z) + sin(phi) in .w
//   [16384]  float pack[2][512][8] : {hx/max, hy/max, hz/max, 0, e0*sp/60, e1*sp/60, e2*sp/60, 0}

__global__ void k_setup1(float* __restrict__ hmat, unsigned* __restrict__ maxslot) {
    int m = threadIdx.x;            // 512 threads, one per light dir
    if (m == 0) *maxslot = 0u;
    int p = m >> 5;                 // phi index (EH=16)
    int t = m & 31;                 // theta index (EW=32)
    float phi = ((float)p * (1.0f / 16.0f)) * PI_F;
    float th  = ((float)t * (1.0f / 32.0f)) * (2.0f * PI_F);
    float sp = sinf(phi), cp = cosf(phi);
    float st = sinf(th),  ct = cosf(th);
    // l = (st*sp, cp, -ct*sp); h = l + (0,0,1), normalized
    float hx = st * sp;
    float hy = cp;
    float hz = 1.0f - ct * sp;
    float inv = rsqrtf(hx * hx + hy * hy + hz * hz);
    float4 v;
    v.x = hx * inv; v.y = hy * inv; v.z = hz * inv; v.w = sp;
    reinterpret_cast<float4*>(hmat)[m] = v;
}

__device__ __forceinline__ void load_normal(const float* __restrict__ normal, size_t pix,
                                            float& nx, float& ny, float& nz) {
    const float* p = normal + pix * 3;
    float c0 = p[0], c1 = p[1], c2 = p[2];
    // channel-reversed, [0,1] -> [-1,1], L2 normalize
    float x = (c2 - 0.5f) * 2.0f;
    float y = (c1 - 0.5f) * 2.0f;
    float z = (c0 - 0.5f) * 2.0f;
    float d2 = x * x + y * y + z * z;
    float inv = d2 > 0.0f ? rsqrtf(d2) : 0.0f;
    nx = x * inv; ny = y * inv; nz = z * inv;
}

__global__ __launch_bounds__(256) void k_max(const float* __restrict__ normal,
                                             const float* __restrict__ hmat,
                                             unsigned* __restrict__ maxslot) {
    int base = blockIdx.x * (256 * PXPT) + (int)threadIdx.x;   // strided pixels per thread
    float nx[PXPT], ny[PXPT], nz[PXPT];
    #pragma unroll
    for (int k = 0; k < PXPT; ++k)
        load_normal(normal, (size_t)(base + k * 256), nx[k], ny[k], nz[k]);

    float mx[PXPT];                                 // independent chains per pixel
    #pragma unroll
    for (int k = 0; k < PXPT; ++k) mx[k] = 0.0f;

    const float4* hm = reinterpret_cast<const float4*>(hmat);
    #pragma unroll 8
    for (int m = 0; m < NL; ++m) {
        float4 h = hm[m];                          // uniform address
        #pragma unroll
        for (int k = 0; k < PXPT; ++k) {
            float s = fmaf(nx[k], h.x, fmaf(ny[k], h.y, nz[k] * h.z));
            mx[k] = fmaxf(mx[k], s);
        }
    }
    float m0 = mx[0];
    #pragma unroll
    for (int k = 1; k < PXPT; ++k) m0 = fmaxf(m0, mx[k]);
    // wave-64 max reduce
    #pragma unroll
    for (int off = 32; off > 0; off >>= 1)
        m0 = fmaxf(m0, __shfl_xor(m0, off));
    if ((threadIdx.x & 63) == 0)
        atomicMax(maxslot, __float_as_uint(m0));   // all candidates >= 0
}

__global__ void k_setup2(const float* __restrict__ env,
                         const float* __restrict__ hmat,
                         const unsigned* __restrict__ maxslot,
                         float* __restrict__ pack) {
    int m = threadIdx.x;            // 512 threads
    float invmax = 1.0f / __uint_as_float(*maxslot);
    float4 h = reinterpret_cast<const float4*>(hmat)[m];
    float sp = h.w;
    #pragma unroll
    for (int b = 0; b < NB; ++b) {
        float* dst = pack + ((size_t)(b * NL + m)) * 8;
        const float* e = env + ((size_t)(b * NL + m)) * 3;
        dst[0] = h.x * invmax;
        dst[1] = h.y * invmax;
        dst[2] = h.z * invmax;
        dst[3] = 0.0f;
        float c = sp * (1.0f / 60.0f);
        dst[4] = e[0] * c;
        dst[5] = e[1] * c;
        dst[6] = e[2] * c;
        dst[7] = 0.0f;
    }
}

__global__ __launch_bounds__(256) void k_shade(const float* __restrict__ normal,
                                               const float* __restrict__ pack,
                                               float* __restrict__ out) {
    int bid = blockIdx.x;
    int blocks_per_batch = HWPX / (256 * PXPT);     // 512
    int b = bid / blocks_per_batch;
    int base_in_b = (bid % blocks_per_batch) * (256 * PXPT) + (int)threadIdx.x;

    float nx[PXPT], ny[PXPT], nz[PXPT];
    #pragma unroll
    for (int k = 0; k < PXPT; ++k)
        load_normal(normal, (size_t)b * HWPX + base_in_b + k * 256, nx[k], ny[k], nz[k]);

    const float* P = pack + (size_t)b * NL * 8;     // uniform per block
    float a0[PXPT], a1[PXPT], a2[PXPT];
    #pragma unroll
    for (int k = 0; k < PXPT; ++k) { a0[k] = 0.0f; a1[k] = 0.0f; a2[k] = 0.0f; }

    #pragma unroll 8
    for (int m = 0; m < NL; ++m) {
        float4 h = *reinterpret_cast<const float4*>(P + (size_t)m * 8);
        float4 e = *reinterpret_cast<const float4*>(P + (size_t)m * 8 + 4);
        #pragma unroll
        for (int k = 0; k < PXPT; ++k) {
            float s = fmaf(nx[k], h.x, fmaf(ny[k], h.y, nz[k] * h.z));
            s = fmaxf(s, 0.0f);                     // relu, already scaled by 1/max
            float s2  = s * s;
            float s4  = s2 * s2;
            float s8  = s4 * s4;
            float s16 = s8 * s8;
            float s32 = s16 * s16;
            float s64 = s32 * s32;
            a0[k] = fmaf(s64, e.x, a0[k]);
            a1[k] = fmaf(s64, e.y, a1[k]);
            a2[k] = fmaf(s64, e.z, a2[k]);
        }
    }
    // out[b][c][h][w]
    float* ob = out + (size_t)b * 3 * HWPX;
    #pragma unroll
    for (int k = 0; k < PXPT; ++k) {
        int p = base_in_b + k * 256;
        ob[0 * HWPX + p] = a0[k];
        ob[1 * HWPX + p] = a1[k];
        ob[2 * HWPX + p] = a2[k];
    }
}

extern "C" void kernel_launch(void* const* d_in, const int* in_sizes, int n_in,
                              void* d_out, int out_size, void* d_ws, size_t ws_size,
                              hipStream_t stream) {
    const float* env    = (const float*)d_in[0];   // (B,16,32,3) f32
    const float* normal = (const float*)d_in[1];   // (B,512,512,3) f32
    float* out = (float*)d_out;                    // (B,3,512,512) f32

    char* ws = (char*)d_ws;
    unsigned* maxslot = (unsigned*)ws;
    float* hmat = (float*)(ws + 256);
    float* pack = (float*)(ws + 16384);

    int nblocks = (NB * HWPX) / (256 * PXPT);      // 1024

    hipLaunchKernelGGL(k_setup1, dim3(1), dim3(NL), 0, stream, hmat, maxslot);
    hipLaunchKernelGGL(k_max, dim3(nblocks), dim3(256), 0, stream, normal, hmat, maxslot);
    hipLaunchKernelGGL(k_setup2, dim3(1), dim3(NL), 0, stream, env, hmat, maxslot, pack);
    hipLaunchKernelGGL(k_shade, dim3(nblocks), dim3(256), 0, stream, normal, pack, out);
}